// Round 2
// baseline (4227.002 us; speedup 1.0000x reference)
//
#include <hip/hip_runtime.h>
#include <math.h>

#define N_NODES 100000
#define N_EDGES 1600000
#define F_IN 256
#define F_H 128
#define F_OUT 40

__device__ __forceinline__ void atomAddF(float* p, float v) {
#if __HIP_DEVICE_COMPILE__
    unsafeAtomicAdd(p, v);   // hw global_atomic_add_f32 on gfx950 (avoid CAS loop)
#else
    atomicAdd(p, v);
#endif
}

// ---- degree / norm ----
__global__ void k_init_deg(float* deg) {
    int i = blockIdx.x * blockDim.x + threadIdx.x;
    if (i < N_NODES) deg[i] = 1.0f;   // self-loop
}

__global__ void k_count(const int* __restrict__ eidx, float* deg) {
    int e = blockIdx.x * blockDim.x + threadIdx.x;
    if (e < N_EDGES) atomAddF(&deg[eidx[N_EDGES + e]], 1.0f);
}

__global__ void k_rsqrt(float* deg) {
    int i = blockIdx.x * blockDim.x + threadIdx.x;
    if (i < N_NODES) deg[i] = rsqrtf(deg[i]);   // deg >= 1 always
}

__global__ void k_norm(const int* __restrict__ eidx, const float* __restrict__ dinv,
                       float* __restrict__ norm) {
    int e = blockIdx.x * blockDim.x + threadIdx.x;
    if (e < N_EDGES) norm[e] = dinv[eidx[e]] * dinv[eidx[N_EDGES + e]];
}

// ---- GEMM1: h1[N,128] = x[N,256] @ W1[256,128] ----
__global__ __launch_bounds__(256) void k_gemm1(const float* __restrict__ x,
                                               const float* __restrict__ W1,
                                               float* __restrict__ h1) {
    __shared__ float xs[64][32];     // 8 KB
    __shared__ float wsm[32][128];   // 16 KB
    const int tid = threadIdx.x;
    const int row0 = blockIdx.x * 64;
    const int c = tid & 63;          // cols c and c+64
    const int rg = tid >> 6;         // 0..3
    const int rbase = rg * 16;
    float acc[16][2];
#pragma unroll
    for (int i = 0; i < 16; ++i) { acc[i][0] = 0.f; acc[i][1] = 0.f; }

    for (int k0 = 0; k0 < F_IN; k0 += 32) {
#pragma unroll
        for (int j = 0; j < 8; ++j) {
            int idx = tid + j * 256;
            int r = idx >> 5, kk = idx & 31;
            int row = row0 + r;
            xs[r][kk] = (row < N_NODES) ? x[row * F_IN + k0 + kk] : 0.f;
        }
#pragma unroll
        for (int j = 0; j < 16; ++j) {
            int idx = tid + j * 256;
            int kk = idx >> 7, cc = idx & 127;
            wsm[kk][cc] = W1[(k0 + kk) * F_H + cc];
        }
        __syncthreads();
#pragma unroll
        for (int kk = 0; kk < 32; kk += 4) {
            float4 xv[16];
#pragma unroll
            for (int i = 0; i < 16; ++i) xv[i] = *(const float4*)(&xs[rbase + i][kk]);
#pragma unroll
            for (int q = 0; q < 4; ++q) {
                float w0 = wsm[kk + q][c];
                float w1v = wsm[kk + q][c + 64];
#pragma unroll
                for (int i = 0; i < 16; ++i) {
                    float xvq = ((const float*)(&xv[i]))[q];
                    acc[i][0] = fmaf(xvq, w0, acc[i][0]);
                    acc[i][1] = fmaf(xvq, w1v, acc[i][1]);
                }
            }
        }
        __syncthreads();
    }
#pragma unroll
    for (int i = 0; i < 16; ++i) {
        int row = row0 + rbase + i;
        if (row < N_NODES) {
            h1[row * F_H + c] = acc[i][0];
            h1[row * F_H + c + 64] = acc[i][1];
        }
    }
}

// ---- self-loop init: agg1 = h1 * dinv^2 ----
__global__ void k_self1(const float* __restrict__ h1, const float* __restrict__ dinv,
                        float* __restrict__ agg1) {
    int idx = blockIdx.x * blockDim.x + threadIdx.x;
    if (idx < N_NODES * F_H) {
        float d = dinv[idx >> 7];
        agg1[idx] = h1[idx] * d * d;
    }
}

// ---- edge scatter layer 1: agg1[dst] += h1[src]*norm ----
__global__ void k_scat1(const int* __restrict__ eidx, const float* __restrict__ norm,
                        const float* __restrict__ h1, float* __restrict__ agg1) {
    int t = blockIdx.x * blockDim.x + threadIdx.x;
    if (t >= N_EDGES * 32) return;
    int e = t >> 5, l = t & 31;
    int s = eidx[e];
    int d = eidx[N_EDGES + e];
    float nm = norm[e];
    float4 v = *(const float4*)(&h1[s * F_H + l * 4]);
    float* dp = &agg1[d * F_H + l * 4];
    atomAddF(dp + 0, v.x * nm);
    atomAddF(dp + 1, v.y * nm);
    atomAddF(dp + 2, v.z * nm);
    atomAddF(dp + 3, v.w * nm);
}

// ---- bias + relu in place ----
__global__ void k_bias_relu(float* agg1, const float* __restrict__ b1) {
    int idx = blockIdx.x * blockDim.x + threadIdx.x;
    if (idx < N_NODES * F_H) {
        float v = agg1[idx] + b1[idx & 127];
        agg1[idx] = v > 0.f ? v : 0.f;
    }
}

// ---- GEMM2: h2[N,40] = h[N,128] @ W2[128,40] ----
__global__ __launch_bounds__(256) void k_gemm2(const float* __restrict__ h,
                                               const float* __restrict__ W2,
                                               float* __restrict__ h2) {
    __shared__ float hs[64][32];       // 8 KB
    __shared__ float w2s[128][40];     // 20 KB (full W2)
    const int tid = threadIdx.x;
    const int row0 = blockIdx.x * 64;
    const int c = tid & 63;            // c < 40 active
    const int rg = tid >> 6;
    const int rbase = rg * 16;
#pragma unroll
    for (int j = 0; j < 20; ++j) {
        int idx = tid + j * 256;
        ((float*)w2s)[idx] = W2[idx];
    }
    float acc[16];
#pragma unroll
    for (int i = 0; i < 16; ++i) acc[i] = 0.f;

    for (int k0 = 0; k0 < F_H; k0 += 32) {
#pragma unroll
        for (int j = 0; j < 8; ++j) {
            int idx = tid + j * 256;
            int r = idx >> 5, kk = idx & 31;
            int row = row0 + r;
            hs[r][kk] = (row < N_NODES) ? h[row * F_H + k0 + kk] : 0.f;
        }
        __syncthreads();
        if (c < F_OUT) {
#pragma unroll
            for (int kk = 0; kk < 32; kk += 4) {
                float4 xv[16];
#pragma unroll
                for (int i = 0; i < 16; ++i) xv[i] = *(const float4*)(&hs[rbase + i][kk]);
#pragma unroll
                for (int q = 0; q < 4; ++q) {
                    float w = w2s[k0 + kk + q][c];
#pragma unroll
                    for (int i = 0; i < 16; ++i) {
                        float xvq = ((const float*)(&xv[i]))[q];
                        acc[i] = fmaf(xvq, w, acc[i]);
                    }
                }
            }
        }
        __syncthreads();
    }
    if (c < F_OUT) {
#pragma unroll
        for (int i = 0; i < 16; ++i) {
            int row = row0 + rbase + i;
            if (row < N_NODES) h2[row * F_OUT + c] = acc[i];
        }
    }
}

// ---- self-loop init layer 2: out = h2 * dinv^2 ----
__global__ void k_self2(const float* __restrict__ h2, const float* __restrict__ dinv,
                        float* __restrict__ out) {
    int idx = blockIdx.x * blockDim.x + threadIdx.x;
    if (idx < N_NODES * F_OUT) {
        float d = dinv[idx / F_OUT];
        out[idx] = h2[idx] * d * d;
    }
}

// ---- edge scatter layer 2: out[dst] += h2[src]*norm ----
__global__ void k_scat2(const int* __restrict__ eidx, const float* __restrict__ norm,
                        const float* __restrict__ h2, float* __restrict__ out) {
    int t = blockIdx.x * blockDim.x + threadIdx.x;
    if (t >= N_EDGES * 10) return;
    int e = t / 10, l = t % 10;
    int s = eidx[e];
    int d = eidx[N_EDGES + e];
    float nm = norm[e];
    float4 v = *(const float4*)(&h2[s * F_OUT + l * 4]);
    float* dp = &out[d * F_OUT + l * 4];
    atomAddF(dp + 0, v.x * nm);
    atomAddF(dp + 1, v.y * nm);
    atomAddF(dp + 2, v.z * nm);
    atomAddF(dp + 3, v.w * nm);
}

// ---- log_softmax per row (wave per row, lanes 0..39 active) ----
__global__ __launch_bounds__(256) void k_lsm(float* __restrict__ out, const float* __restrict__ b2) {
    int gtid = blockIdx.x * blockDim.x + threadIdx.x;
    int row = gtid >> 6;
    int lane = threadIdx.x & 63;
    if (row >= N_NODES) return;
    float v = -INFINITY;
    if (lane < F_OUT) v = out[row * F_OUT + lane] + b2[lane];
    float m = v;
#pragma unroll
    for (int o = 32; o > 0; o >>= 1) m = fmaxf(m, __shfl_xor(m, o, 64));
    float ev = (lane < F_OUT) ? expf(v - m) : 0.f;
    float ssum = ev;
#pragma unroll
    for (int o = 32; o > 0; o >>= 1) ssum += __shfl_xor(ssum, o, 64);
    if (lane < F_OUT) out[row * F_OUT + lane] = v - m - logf(ssum);
}

extern "C" void kernel_launch(void* const* d_in, const int* in_sizes, int n_in,
                              void* d_out, int out_size, void* d_ws, size_t ws_size,
                              hipStream_t stream) {
    const float* x = (const float*)d_in[0];
    const int* eidx = (const int*)d_in[1];   // harness delivers integer inputs as int32
    const float* W1 = (const float*)d_in[2];
    const float* b1 = (const float*)d_in[3];
    const float* W2 = (const float*)d_in[4];
    const float* b2 = (const float*)d_in[5];
    float* out = (float*)d_out;

    float* ws = (float*)d_ws;
    float* dinv = ws;                          // 100000
    float* norm = ws + 100000;                 // 1.6M
    float* h1   = ws + 1700000;                // 12.8M (16B-aligned offset)
    float* agg1 = h1 + (size_t)N_NODES * F_H;  // 12.8M
    float* h2   = h1;                          // alias: h1 dead once k_gemm2 reads agg1

    k_init_deg<<<(N_NODES + 255) / 256, 256, 0, stream>>>(dinv);
    k_count<<<(N_EDGES + 255) / 256, 256, 0, stream>>>(eidx, dinv);
    k_rsqrt<<<(N_NODES + 255) / 256, 256, 0, stream>>>(dinv);
    k_norm<<<(N_EDGES + 255) / 256, 256, 0, stream>>>(eidx, dinv, norm);

    k_gemm1<<<(N_NODES + 63) / 64, 256, 0, stream>>>(x, W1, h1);
    k_self1<<<(N_NODES * F_H) / 256, 256, 0, stream>>>(h1, dinv, agg1);
    k_scat1<<<(N_EDGES * 32) / 256, 256, 0, stream>>>(eidx, norm, h1, agg1);
    k_bias_relu<<<(N_NODES * F_H) / 256, 256, 0, stream>>>(agg1, b1);

    k_gemm2<<<(N_NODES + 63) / 64, 256, 0, stream>>>(agg1, W2, h2);
    k_self2<<<(N_NODES * F_OUT) / 256, 256, 0, stream>>>(h2, dinv, out);
    k_scat2<<<(N_EDGES * 10) / 256, 256, 0, stream>>>(eidx, norm, h2, out);
    k_lsm<<<(N_NODES * 64 + 255) / 256, 256, 0, stream>>>(out, b2);
}

// Round 3
// 845.555 us; speedup vs baseline: 4.9991x; 4.9991x over previous
//
#include <hip/hip_runtime.h>
#include <math.h>

#define N_NODES 100000
#define N_EDGES 1600000
#define F_IN 256
#define F_H 128
#define F_OUT 40
#define SCAN_CHUNK 1024
#define NCHUNK ((N_NODES + SCAN_CHUNK - 1) / SCAN_CHUNK)   // 98

// ---- zero int array ----
__global__ void k_zero(int* p, int n) {
    int i = blockIdx.x * blockDim.x + threadIdx.x;
    if (i < n) p[i] = 0;
}

// ---- int degree count over dst ----
__global__ void k_deg(const int* __restrict__ eidx, int* degi) {
    int e = blockIdx.x * blockDim.x + threadIdx.x;
    if (e < N_EDGES) atomicAdd(&degi[eidx[N_EDGES + e]], 1);
}

// ---- dinv = rsqrt(deg + 1 [self-loop]) ----
__global__ void k_dinv(const int* __restrict__ degi, float* __restrict__ dinv) {
    int i = blockIdx.x * blockDim.x + threadIdx.x;
    if (i < N_NODES) dinv[i] = rsqrtf((float)degi[i] + 1.0f);
}

// ---- scan level 1: per-chunk totals ----
__global__ __launch_bounds__(256) void k_chunk_sums(const int* __restrict__ degi,
                                                    int* __restrict__ chunkSums) {
    __shared__ int lds[256];
    int b = blockIdx.x, t = threadIdx.x;
    int base = b * SCAN_CHUNK;
    int s = 0;
#pragma unroll
    for (int j = 0; j < 4; ++j) {
        int i = base + j * 256 + t;
        if (i < N_NODES) s += degi[i];
    }
    lds[t] = s;
    __syncthreads();
    for (int off = 128; off > 0; off >>= 1) {
        if (t < off) lds[t] += lds[t + off];
        __syncthreads();
    }
    if (t == 0) chunkSums[b] = lds[0];
}

// ---- scan level 2: exclusive scan of chunk sums (in place) ----
__global__ __launch_bounds__(128) void k_scan_sums(int* chunkSums) {
    __shared__ int lds[NCHUNK];
    int t = threadIdx.x;
    if (t < NCHUNK) lds[t] = chunkSums[t];
    __syncthreads();
    if (t == 0) {
        int run = 0;
        for (int i = 0; i < NCHUNK; ++i) { int c = lds[i]; lds[i] = run; run += c; }
    }
    __syncthreads();
    if (t < NCHUNK) chunkSums[t] = lds[t];
}

// ---- scan level 3: per-element exclusive prefix -> rowptr & cursor ----
__global__ __launch_bounds__(256) void k_scan_final(const int* __restrict__ degi,
                                                    const int* __restrict__ chunkOff,
                                                    int* __restrict__ rowptr,
                                                    int* __restrict__ cursor) {
    __shared__ int tsum[256];
    int b = blockIdx.x, t = threadIdx.x;
    int base = b * SCAN_CHUNK;
    int v[4];
    int s = 0;
#pragma unroll
    for (int j = 0; j < 4; ++j) {
        int i = base + t * 4 + j;
        v[j] = (i < N_NODES) ? degi[i] : 0;
        s += v[j];
    }
    tsum[t] = s;
    __syncthreads();
    for (int off = 1; off < 256; off <<= 1) {
        int val = 0;
        if (t >= off) val = tsum[t - off];
        __syncthreads();
        if (t >= off) tsum[t] += val;
        __syncthreads();
    }
    int run = chunkOff[b] + ((t == 0) ? 0 : tsum[t - 1]);
#pragma unroll
    for (int j = 0; j < 4; ++j) {
        int i = base + t * 4 + j;
        if (i < N_NODES) { rowptr[i] = run; cursor[i] = run; }
        run += v[j];
    }
    if (b == 0 && t == 0) rowptr[N_NODES] = N_EDGES;
}

// ---- CSR fill (also computes norm) ----
__global__ void k_fill(const int* __restrict__ eidx, const float* __restrict__ dinv,
                       int* cursor, int* __restrict__ csr_src, float* __restrict__ csr_norm) {
    int e = blockIdx.x * blockDim.x + threadIdx.x;
    if (e >= N_EDGES) return;
    int s = eidx[e], d = eidx[N_EDGES + e];
    int pos = atomicAdd(&cursor[d], 1);
    csr_src[pos] = s;
    csr_norm[pos] = dinv[s] * dinv[d];
}

// ---- GEMM1: h1[N,128] = x[N,256] @ W1[256,128] ----
__global__ __launch_bounds__(256) void k_gemm1(const float* __restrict__ x,
                                               const float* __restrict__ W1,
                                               float* __restrict__ h1) {
    __shared__ float xs[64][32];
    __shared__ float wsm[32][128];
    const int tid = threadIdx.x;
    const int row0 = blockIdx.x * 64;
    const int c = tid & 63;
    const int rg = tid >> 6;
    const int rbase = rg * 16;
    float acc[16][2];
#pragma unroll
    for (int i = 0; i < 16; ++i) { acc[i][0] = 0.f; acc[i][1] = 0.f; }

    for (int k0 = 0; k0 < F_IN; k0 += 32) {
#pragma unroll
        for (int j = 0; j < 8; ++j) {
            int idx = tid + j * 256;
            int r = idx >> 5, kk = idx & 31;
            int row = row0 + r;
            xs[r][kk] = (row < N_NODES) ? x[row * F_IN + k0 + kk] : 0.f;
        }
#pragma unroll
        for (int j = 0; j < 16; ++j) {
            int idx = tid + j * 256;
            int kk = idx >> 7, cc = idx & 127;
            wsm[kk][cc] = W1[(k0 + kk) * F_H + cc];
        }
        __syncthreads();
#pragma unroll
        for (int kk = 0; kk < 32; kk += 4) {
            float4 xv[16];
#pragma unroll
            for (int i = 0; i < 16; ++i) xv[i] = *(const float4*)(&xs[rbase + i][kk]);
#pragma unroll
            for (int q = 0; q < 4; ++q) {
                float w0 = wsm[kk + q][c];
                float w1v = wsm[kk + q][c + 64];
#pragma unroll
                for (int i = 0; i < 16; ++i) {
                    float xvq = ((const float*)(&xv[i]))[q];
                    acc[i][0] = fmaf(xvq, w0, acc[i][0]);
                    acc[i][1] = fmaf(xvq, w1v, acc[i][1]);
                }
            }
        }
        __syncthreads();
    }
#pragma unroll
    for (int i = 0; i < 16; ++i) {
        int row = row0 + rbase + i;
        if (row < N_NODES) {
            h1[row * F_H + c] = acc[i][0];
            h1[row * F_H + c + 64] = acc[i][1];
        }
    }
}

// ---- SpMM1 (gather) + self-loop + bias + relu ----
__global__ __launch_bounds__(128) void k_spmm1(const int* __restrict__ rowptr,
                                               const int* __restrict__ csr_src,
                                               const float* __restrict__ csr_norm,
                                               const float* __restrict__ h1,
                                               const float* __restrict__ dinv,
                                               const float* __restrict__ b1,
                                               float* __restrict__ agg1) {
    int node = blockIdx.x;
    int t = threadIdx.x;
    int beg = rowptr[node], end = rowptr[node + 1];
    float d = dinv[node];
    float acc = h1[(size_t)node * F_H + t] * d * d;   // self loop
    int i = beg;
    for (; i + 1 < end; i += 2) {
        int s0 = csr_src[i], s1 = csr_src[i + 1];
        float n0 = csr_norm[i], n1 = csr_norm[i + 1];
        float a0 = h1[(size_t)s0 * F_H + t];
        float a1 = h1[(size_t)s1 * F_H + t];
        acc = fmaf(a0, n0, acc);
        acc = fmaf(a1, n1, acc);
    }
    if (i < end) {
        int s0 = csr_src[i];
        acc = fmaf(h1[(size_t)s0 * F_H + t], csr_norm[i], acc);
    }
    float v = acc + b1[t];
    agg1[(size_t)node * F_H + t] = v > 0.f ? v : 0.f;
}

// ---- GEMM2: h2[N,40] = h[N,128] @ W2[128,40] ----
__global__ __launch_bounds__(256) void k_gemm2(const float* __restrict__ h,
                                               const float* __restrict__ W2,
                                               float* __restrict__ h2) {
    __shared__ float hs[64][32];
    __shared__ float w2s[128][40];
    const int tid = threadIdx.x;
    const int row0 = blockIdx.x * 64;
    const int c = tid & 63;
    const int rg = tid >> 6;
    const int rbase = rg * 16;
#pragma unroll
    for (int j = 0; j < 20; ++j) {
        int idx = tid + j * 256;
        ((float*)w2s)[idx] = W2[idx];
    }
    float acc[16];
#pragma unroll
    for (int i = 0; i < 16; ++i) acc[i] = 0.f;

    for (int k0 = 0; k0 < F_H; k0 += 32) {
#pragma unroll
        for (int j = 0; j < 8; ++j) {
            int idx = tid + j * 256;
            int r = idx >> 5, kk = idx & 31;
            int row = row0 + r;
            hs[r][kk] = (row < N_NODES) ? h[row * F_H + k0 + kk] : 0.f;
        }
        __syncthreads();
        if (c < F_OUT) {
#pragma unroll
            for (int kk = 0; kk < 32; kk += 4) {
                float4 xv[16];
#pragma unroll
                for (int i = 0; i < 16; ++i) xv[i] = *(const float4*)(&hs[rbase + i][kk]);
#pragma unroll
                for (int q = 0; q < 4; ++q) {
                    float w = w2s[k0 + kk + q][c];
#pragma unroll
                    for (int i = 0; i < 16; ++i) {
                        float xvq = ((const float*)(&xv[i]))[q];
                        acc[i] = fmaf(xvq, w, acc[i]);
                    }
                }
            }
        }
        __syncthreads();
    }
    if (c < F_OUT) {
#pragma unroll
        for (int i = 0; i < 16; ++i) {
            int row = row0 + rbase + i;
            if (row < N_NODES) h2[row * F_OUT + c] = acc[i];
        }
    }
}

// ---- SpMM2 (gather) + self-loop + b2 + log_softmax, wave per node ----
__global__ __launch_bounds__(256) void k_spmm2_lsm(const int* __restrict__ rowptr,
                                                   const int* __restrict__ csr_src,
                                                   const float* __restrict__ csr_norm,
                                                   const float* __restrict__ h2,
                                                   const float* __restrict__ dinv,
                                                   const float* __restrict__ b2,
                                                   float* __restrict__ out) {
    int wave = threadIdx.x >> 6;
    int node = blockIdx.x * 4 + wave;
    int lane = threadIdx.x & 63;
    if (node >= N_NODES) return;
    int beg = rowptr[node], end = rowptr[node + 1];
    float d = dinv[node];
    float acc = 0.f;
    if (lane < F_OUT) acc = h2[(size_t)node * F_OUT + lane] * d * d;
    int i = beg;
    for (; i + 1 < end; i += 2) {
        int s0 = csr_src[i], s1 = csr_src[i + 1];
        float n0 = csr_norm[i], n1 = csr_norm[i + 1];
        float a0 = 0.f, a1 = 0.f;
        if (lane < F_OUT) {
            a0 = h2[(size_t)s0 * F_OUT + lane];
            a1 = h2[(size_t)s1 * F_OUT + lane];
        }
        acc = fmaf(a0, n0, acc);
        acc = fmaf(a1, n1, acc);
    }
    if (i < end && lane < F_OUT) {
        acc = fmaf(h2[(size_t)csr_src[i] * F_OUT + lane], csr_norm[i], acc);
    }
    float v = (lane < F_OUT) ? acc + b2[lane] : -INFINITY;
    float m = v;
#pragma unroll
    for (int o = 32; o > 0; o >>= 1) m = fmaxf(m, __shfl_xor(m, o, 64));
    float ev = (lane < F_OUT) ? expf(v - m) : 0.f;
    float ssum = ev;
#pragma unroll
    for (int o = 32; o > 0; o >>= 1) ssum += __shfl_xor(ssum, o, 64);
    if (lane < F_OUT) out[(size_t)node * F_OUT + lane] = v - m - logf(ssum);
}

extern "C" void kernel_launch(void* const* d_in, const int* in_sizes, int n_in,
                              void* d_out, int out_size, void* d_ws, size_t ws_size,
                              hipStream_t stream) {
    const float* x = (const float*)d_in[0];
    const int* eidx = (const int*)d_in[1];   // int32 from harness
    const float* W1 = (const float*)d_in[2];
    const float* b1 = (const float*)d_in[3];
    const float* W2 = (const float*)d_in[4];
    const float* b2 = (const float*)d_in[5];
    float* out = (float*)d_out;

    char* ws = (char*)d_ws;
    int*   degi      = (int*)  (ws);                          // 100000
    int*   chunkSums = (int*)  (ws + 400000);                 // 128
    int*   rowptr    = (int*)  (ws + 400512);                 // 100001 (pad to 100004)
    int*   cursor    = (int*)  (ws + 800528);                 // 100000
    int*   csr_src   = (int*)  (ws + 1200528);                // 1.6M
    float* csr_norm  = (float*)(ws + 7600528);                // 1.6M
    float* dinv      = (float*)(ws + 14000528);               // 100000
    float* h1        = (float*)(ws + 14400528);               // 12.8M
    float* agg1     = (float*)(ws + 65600528);                // 12.8M
    float* h2        = h1;                                    // alias: h1 dead after spmm1

    k_zero<<<(N_NODES + 255) / 256, 256, 0, stream>>>(degi, N_NODES);
    k_deg<<<(N_EDGES + 255) / 256, 256, 0, stream>>>(eidx, degi);
    k_dinv<<<(N_NODES + 255) / 256, 256, 0, stream>>>(degi, dinv);
    k_chunk_sums<<<NCHUNK, 256, 0, stream>>>(degi, chunkSums);
    k_scan_sums<<<1, 128, 0, stream>>>(chunkSums);
    k_scan_final<<<NCHUNK, 256, 0, stream>>>(degi, chunkSums, rowptr, cursor);
    k_fill<<<(N_EDGES + 255) / 256, 256, 0, stream>>>(eidx, dinv, cursor, csr_src, csr_norm);

    k_gemm1<<<(N_NODES + 63) / 64, 256, 0, stream>>>(x, W1, h1);
    k_spmm1<<<N_NODES, 128, 0, stream>>>(rowptr, csr_src, csr_norm, h1, dinv, b1, agg1);
    k_gemm2<<<(N_NODES + 63) / 64, 256, 0, stream>>>(agg1, W2, h2);
    k_spmm2_lsm<<<(N_NODES + 3) / 4, 256, 0, stream>>>(rowptr, csr_src, csr_norm, h2, dinv, b2, out);
}

// Round 4
// 616.675 us; speedup vs baseline: 6.8545x; 1.3712x over previous
//
#include <hip/hip_runtime.h>
#include <math.h>

#define N_NODES 100000
#define N_EDGES 1600000
#define F_IN 256
#define F_H 128
#define F_OUT 40
#define SCAN_CHUNK 1024
#define NCHUNK ((N_NODES + SCAN_CHUNK - 1) / SCAN_CHUNK)   // 98

typedef __attribute__((ext_vector_type(8))) short bf16x8;
typedef __attribute__((ext_vector_type(4))) float floatx4;

__device__ __forceinline__ unsigned short f2bf(float f) {
    unsigned int u = __float_as_uint(f);
    u += 0x7fffu + ((u >> 16) & 1u);          // RNE (finite inputs)
    return (unsigned short)(u >> 16);
}

// ---- zero int array ----
__global__ void k_zero(int* p, int n) {
    int i = blockIdx.x * blockDim.x + threadIdx.x;
    if (i < n) p[i] = 0;
}

// ---- int degree count over dst ----
__global__ void k_deg(const int* __restrict__ eidx, int* degi) {
    int e = blockIdx.x * blockDim.x + threadIdx.x;
    if (e < N_EDGES) atomicAdd(&degi[eidx[N_EDGES + e]], 1);
}

// ---- dinv = rsqrt(deg + 1 [self-loop]) ----
__global__ void k_dinv(const int* __restrict__ degi, float* __restrict__ dinv) {
    int i = blockIdx.x * blockDim.x + threadIdx.x;
    if (i < N_NODES) dinv[i] = rsqrtf((float)degi[i] + 1.0f);
}

// ---- scan level 1 ----
__global__ __launch_bounds__(256) void k_chunk_sums(const int* __restrict__ degi,
                                                    int* __restrict__ chunkSums) {
    __shared__ int lds[256];
    int b = blockIdx.x, t = threadIdx.x;
    int base = b * SCAN_CHUNK;
    int s = 0;
#pragma unroll
    for (int j = 0; j < 4; ++j) {
        int i = base + j * 256 + t;
        if (i < N_NODES) s += degi[i];
    }
    lds[t] = s;
    __syncthreads();
    for (int off = 128; off > 0; off >>= 1) {
        if (t < off) lds[t] += lds[t + off];
        __syncthreads();
    }
    if (t == 0) chunkSums[b] = lds[0];
}

// ---- scan level 2 ----
__global__ __launch_bounds__(128) void k_scan_sums(int* chunkSums) {
    __shared__ int lds[NCHUNK];
    int t = threadIdx.x;
    if (t < NCHUNK) lds[t] = chunkSums[t];
    __syncthreads();
    if (t == 0) {
        int run = 0;
        for (int i = 0; i < NCHUNK; ++i) { int c = lds[i]; lds[i] = run; run += c; }
    }
    __syncthreads();
    if (t < NCHUNK) chunkSums[t] = lds[t];
}

// ---- scan level 3 ----
__global__ __launch_bounds__(256) void k_scan_final(const int* __restrict__ degi,
                                                    const int* __restrict__ chunkOff,
                                                    int* __restrict__ rowptr,
                                                    int* __restrict__ cursor) {
    __shared__ int tsum[256];
    int b = blockIdx.x, t = threadIdx.x;
    int base = b * SCAN_CHUNK;
    int v[4];
    int s = 0;
#pragma unroll
    for (int j = 0; j < 4; ++j) {
        int i = base + t * 4 + j;
        v[j] = (i < N_NODES) ? degi[i] : 0;
        s += v[j];
    }
    tsum[t] = s;
    __syncthreads();
    for (int off = 1; off < 256; off <<= 1) {
        int val = 0;
        if (t >= off) val = tsum[t - off];
        __syncthreads();
        if (t >= off) tsum[t] += val;
        __syncthreads();
    }
    int run = chunkOff[b] + ((t == 0) ? 0 : tsum[t - 1]);
#pragma unroll
    for (int j = 0; j < 4; ++j) {
        int i = base + t * 4 + j;
        if (i < N_NODES) { rowptr[i] = run; cursor[i] = run; }
        run += v[j];
    }
    if (b == 0 && t == 0) rowptr[N_NODES] = N_EDGES;
}

// ---- CSR fill (also computes norm) ----
__global__ void k_fill(const int* __restrict__ eidx, const float* __restrict__ dinv,
                       int* cursor, int* __restrict__ csr_src, float* __restrict__ csr_norm) {
    int e = blockIdx.x * blockDim.x + threadIdx.x;
    if (e >= N_EDGES) return;
    int s = eidx[e], d = eidx[N_EDGES + e];
    int pos = atomicAdd(&cursor[d], 1);
    csr_src[pos] = s;
    csr_norm[pos] = dinv[s] * dinv[d];
}

// ---- W1 [256][128] fp32 -> W1t [128][256] bf16 ----
__global__ void k_cvt_w1(const float* __restrict__ W1, short* __restrict__ W1t) {
    int idx = blockIdx.x * blockDim.x + threadIdx.x;   // 32768
    int n = idx >> 8, k = idx & 255;
    W1t[n * 256 + k] = (short)f2bf(W1[k * 128 + n]);
}

// ---- W2 [128][40] fp32 -> W2t [48][128] bf16 (zero-padded cols 40..47) ----
__global__ void k_cvt_w2(const float* __restrict__ W2, short* __restrict__ W2t) {
    int idx = blockIdx.x * blockDim.x + threadIdx.x;   // 6144
    if (idx >= 48 * 128) return;
    int n = idx >> 7, k = idx & 127;
    float v = (n < F_OUT) ? W2[k * F_OUT + n] : 0.f;
    W2t[n * 128 + k] = (short)f2bf(v);
}

// ---- GEMM1 (MFMA bf16): h1[N,128] = x[N,256] @ W1 ----
// block: 256 thr (4 waves). tile M=64, N=128. wave w -> cols w*32..w*32+31.
__global__ __launch_bounds__(256) void k_gemm1_mfma(const float* __restrict__ x,
                                                    const short* __restrict__ W1t,
                                                    float* __restrict__ h1) {
    __shared__ short As[64 * 40];    // rows padded to 40 bf16 (80 B, 16B-aligned, 2-way banks)
    __shared__ short Bs[128 * 40];
    const int tid = threadIdx.x;
    const int row0 = blockIdx.x * 64;
    const int w = tid >> 6, l = tid & 63;
    const int l15 = l & 15, q = l >> 4;
    // A staging coords: 8 floats/thread
    const int ar = tid >> 2;             // 0..63
    const int ak = (tid & 3) * 8;        // 0,8,16,24
    // B staging coords: 16 bf16/thread
    const int bn = tid >> 1;             // 0..127
    const int bk = (tid & 1) * 16;

    floatx4 acc[4][2];
#pragma unroll
    for (int mt = 0; mt < 4; ++mt)
#pragma unroll
        for (int nt = 0; nt < 2; ++nt) acc[mt][nt] = (floatx4)0.f;

    const bool arow_ok = (row0 + ar) < N_NODES;
    const float* xp = x + (size_t)(row0 + ar) * F_IN;

    for (int k0 = 0; k0 < F_IN; k0 += 32) {
        // stage A (fp32 -> bf16)
        bf16x8 av;
        if (arow_ok) {
            float4 f0 = *(const float4*)(xp + k0 + ak);
            float4 f1 = *(const float4*)(xp + k0 + ak + 4);
            av[0] = (short)f2bf(f0.x); av[1] = (short)f2bf(f0.y);
            av[2] = (short)f2bf(f0.z); av[3] = (short)f2bf(f0.w);
            av[4] = (short)f2bf(f1.x); av[5] = (short)f2bf(f1.y);
            av[6] = (short)f2bf(f1.z); av[7] = (short)f2bf(f1.w);
        } else {
            av = (bf16x8)0;
        }
        *(bf16x8*)&As[ar * 40 + ak] = av;
        // stage B (already bf16, transposed)
        *(bf16x8*)&Bs[bn * 40 + bk]     = *(const bf16x8*)&W1t[bn * 256 + k0 + bk];
        *(bf16x8*)&Bs[bn * 40 + bk + 8] = *(const bf16x8*)&W1t[bn * 256 + k0 + bk + 8];
        __syncthreads();

        bf16x8 af[4], bfr[2];
#pragma unroll
        for (int mt = 0; mt < 4; ++mt)
            af[mt] = *(const bf16x8*)&As[(mt * 16 + l15) * 40 + q * 8];
#pragma unroll
        for (int nt = 0; nt < 2; ++nt)
            bfr[nt] = *(const bf16x8*)&Bs[(w * 32 + nt * 16 + l15) * 40 + q * 8];
#pragma unroll
        for (int mt = 0; mt < 4; ++mt)
#pragma unroll
            for (int nt = 0; nt < 2; ++nt)
                acc[mt][nt] = __builtin_amdgcn_mfma_f32_16x16x32_bf16(af[mt], bfr[nt], acc[mt][nt], 0, 0, 0);
        __syncthreads();
    }
#pragma unroll
    for (int mt = 0; mt < 4; ++mt) {
#pragma unroll
        for (int nt = 0; nt < 2; ++nt) {
            int col = w * 32 + nt * 16 + l15;
#pragma unroll
            for (int r = 0; r < 4; ++r) {
                int row = row0 + mt * 16 + q * 4 + r;
                if (row < N_NODES) h1[(size_t)row * F_H + col] = acc[mt][nt][r];
            }
        }
    }
}

// ---- SpMM1 (gather) + self-loop + bias + relu -> bf16 ----
__global__ __launch_bounds__(128) void k_spmm1(const int* __restrict__ rowptr,
                                               const int* __restrict__ csr_src,
                                               const float* __restrict__ csr_norm,
                                               const float* __restrict__ h1,
                                               const float* __restrict__ dinv,
                                               const float* __restrict__ b1,
                                               unsigned short* __restrict__ agg1b) {
    int node = blockIdx.x;
    int t = threadIdx.x;
    int beg = rowptr[node], end = rowptr[node + 1];
    float d = dinv[node];
    float acc = h1[(size_t)node * F_H + t] * d * d;   // self loop
    int i = beg;
    for (; i + 1 < end; i += 2) {
        int s0 = csr_src[i], s1 = csr_src[i + 1];
        float n0 = csr_norm[i], n1 = csr_norm[i + 1];
        float a0 = h1[(size_t)s0 * F_H + t];
        float a1 = h1[(size_t)s1 * F_H + t];
        acc = fmaf(a0, n0, acc);
        acc = fmaf(a1, n1, acc);
    }
    if (i < end) {
        int s0 = csr_src[i];
        acc = fmaf(h1[(size_t)s0 * F_H + t], csr_norm[i], acc);
    }
    float v = acc + b1[t];
    v = v > 0.f ? v : 0.f;
    agg1b[(size_t)node * F_H + t] = f2bf(v);
}

// ---- GEMM2 (MFMA bf16): h2[N,40] = agg1b[N,128] @ W2 ----
// block: 256 thr (4 waves). tile M=128 (wave w -> rows w*32..+31), N=48 (40 + pad).
__global__ __launch_bounds__(256) void k_gemm2_mfma(const unsigned short* __restrict__ agg1b,
                                                    const short* __restrict__ W2t,
                                                    float* __restrict__ h2) {
    __shared__ short As[128 * 40];     // 10 KB
    __shared__ short Bs[48 * 136];     // 12.75 KB (full W2t, k-padded row stride 272 B)
    const int tid = threadIdx.x;
    const int row0 = blockIdx.x * 128;
    const int w = tid >> 6, l = tid & 63;
    const int l15 = l & 15, q = l >> 4;
    const int ar = tid >> 1;             // 0..127
    const int ak = (tid & 1) * 16;

    // stage all of W2t once
#pragma unroll
    for (int i = 0; i < 3; ++i) {
        int c = tid * 3 + i;             // 0..767 chunks of 8 bf16
        int n = c >> 4, koff = (c & 15) * 8;
        *(bf16x8*)&Bs[n * 136 + koff] = *(const bf16x8*)&W2t[n * 128 + koff];
    }

    floatx4 acc[2][3];
#pragma unroll
    for (int a = 0; a < 2; ++a)
#pragma unroll
        for (int nt = 0; nt < 3; ++nt) acc[a][nt] = (floatx4)0.f;

    const bool arow_ok = (row0 + ar) < N_NODES;
    const unsigned short* ap = agg1b + (size_t)(row0 + ar) * F_H;

    for (int k0 = 0; k0 < F_H; k0 += 32) {
        bf16x8 a0, a1;
        if (arow_ok) {
            a0 = *(const bf16x8*)(ap + k0 + ak);
            a1 = *(const bf16x8*)(ap + k0 + ak + 8);
        } else {
            a0 = (bf16x8)0; a1 = (bf16x8)0;
        }
        *(bf16x8*)&As[ar * 40 + ak]     = a0;
        *(bf16x8*)&As[ar * 40 + ak + 8] = a1;
        __syncthreads();

        bf16x8 af[2], bfr[3];
#pragma unroll
        for (int a = 0; a < 2; ++a)
            af[a] = *(const bf16x8*)&As[((w * 2 + a) * 16 + l15) * 40 + q * 8];
#pragma unroll
        for (int nt = 0; nt < 3; ++nt)
            bfr[nt] = *(const bf16x8*)&Bs[(nt * 16 + l15) * 136 + k0 + q * 8];
#pragma unroll
        for (int a = 0; a < 2; ++a)
#pragma unroll
            for (int nt = 0; nt < 3; ++nt)
                acc[a][nt] = __builtin_amdgcn_mfma_f32_16x16x32_bf16(af[a], bfr[nt], acc[a][nt], 0, 0, 0);
        __syncthreads();
    }
#pragma unroll
    for (int a = 0; a < 2; ++a) {
#pragma unroll
        for (int nt = 0; nt < 3; ++nt) {
            int col = nt * 16 + l15;
#pragma unroll
            for (int r = 0; r < 4; ++r) {
                int row = row0 + (w * 2 + a) * 16 + q * 4 + r;
                if (row < N_NODES && col < F_OUT) h2[(size_t)row * F_OUT + col] = acc[a][nt][r];
            }
        }
    }
}

// ---- SpMM2 (gather) + self-loop + b2 + log_softmax, wave per node ----
__global__ __launch_bounds__(256) void k_spmm2_lsm(const int* __restrict__ rowptr,
                                                   const int* __restrict__ csr_src,
                                                   const float* __restrict__ csr_norm,
                                                   const float* __restrict__ h2,
                                                   const float* __restrict__ dinv,
                                                   const float* __restrict__ b2,
                                                   float* __restrict__ out) {
    int wave = threadIdx.x >> 6;
    int node = blockIdx.x * 4 + wave;
    int lane = threadIdx.x & 63;
    if (node >= N_NODES) return;
    int beg = rowptr[node], end = rowptr[node + 1];
    float d = dinv[node];
    float acc = 0.f;
    if (lane < F_OUT) acc = h2[(size_t)node * F_OUT + lane] * d * d;
    int i = beg;
    for (; i + 1 < end; i += 2) {
        int s0 = csr_src[i], s1 = csr_src[i + 1];
        float n0 = csr_norm[i], n1 = csr_norm[i + 1];
        float a0 = 0.f, a1 = 0.f;
        if (lane < F_OUT) {
            a0 = h2[(size_t)s0 * F_OUT + lane];
            a1 = h2[(size_t)s1 * F_OUT + lane];
        }
        acc = fmaf(a0, n0, acc);
        acc = fmaf(a1, n1, acc);
    }
    if (i < end && lane < F_OUT) {
        acc = fmaf(h2[(size_t)csr_src[i] * F_OUT + lane], csr_norm[i], acc);
    }
    float v = (lane < F_OUT) ? acc + b2[lane] : -INFINITY;
    float m = v;
#pragma unroll
    for (int o = 32; o > 0; o >>= 1) m = fmaxf(m, __shfl_xor(m, o, 64));
    float ev = (lane < F_OUT) ? expf(v - m) : 0.f;
    float ssum = ev;
#pragma unroll
    for (int o = 32; o > 0; o >>= 1) ssum += __shfl_xor(ssum, o, 64);
    if (lane < F_OUT) out[(size_t)node * F_OUT + lane] = v - m - logf(ssum);
}

extern "C" void kernel_launch(void* const* d_in, const int* in_sizes, int n_in,
                              void* d_out, int out_size, void* d_ws, size_t ws_size,
                              hipStream_t stream) {
    const float* x = (const float*)d_in[0];
    const int* eidx = (const int*)d_in[1];   // int32 from harness
    const float* W1 = (const float*)d_in[2];
    const float* b1 = (const float*)d_in[3];
    const float* W2 = (const float*)d_in[4];
    const float* b2 = (const float*)d_in[5];
    float* out = (float*)d_out;

    char* ws = (char*)d_ws;
    int*   degi      = (int*)  (ws);                 // 100000 ints
    int*   chunkSums = (int*)  (ws + 400000);        // 128
    int*   rowptr    = (int*)  (ws + 400512);        // 100001
    int*   cursor    = (int*)  (ws + 800528);        // 100000
    int*   csr_src   = (int*)  (ws + 1200528);       // 1.6M
    float* csr_norm  = (float*)(ws + 7600528);       // 1.6M
    float* dinv      = (float*)(ws + 14000528);      // 100000
    short* W1t       = (short*)(ws + 14400528);      // 32768 bf16
    short* W2t       = (short*)(ws + 14466064);      // 6144 bf16
    float* h1        = (float*)(ws + 14478352);      // 12.8M floats
    unsigned short* agg1b = (unsigned short*)(ws + 65678352);  // 12.8M bf16
    float* h2        = (float*)(ws + 91278352);      // 4M floats

    k_zero<<<(N_NODES + 255) / 256, 256, 0, stream>>>(degi, N_NODES);
    k_deg<<<(N_EDGES + 255) / 256, 256, 0, stream>>>(eidx, degi);
    k_dinv<<<(N_NODES + 255) / 256, 256, 0, stream>>>(degi, dinv);
    k_chunk_sums<<<NCHUNK, 256, 0, stream>>>(degi, chunkSums);
    k_scan_sums<<<1, 128, 0, stream>>>(chunkSums);
    k_scan_final<<<NCHUNK, 256, 0, stream>>>(degi, chunkSums, rowptr, cursor);
    k_fill<<<(N_EDGES + 255) / 256, 256, 0, stream>>>(eidx, dinv, cursor, csr_src, csr_norm);

    k_cvt_w1<<<128, 256, 0, stream>>>(W1, W1t);
    k_cvt_w2<<<24, 256, 0, stream>>>(W2, W2t);

    k_gemm1_mfma<<<(N_NODES + 63) / 64, 256, 0, stream>>>(x, W1t, h1);
    k_spmm1<<<N_NODES, 128, 0, stream>>>(rowptr, csr_src, csr_norm, h1, dinv, b1, agg1b);
    k_gemm2_mfma<<<(N_NODES + 127) / 128, 256, 0, stream>>>(agg1b, W2t, h2);
    k_spmm2_lsm<<<(N_NODES + 3) / 4, 256, 0, stream>>>(rowptr, csr_src, csr_norm, h2, dinv, b2, out);
}

// Round 5
// 525.982 us; speedup vs baseline: 8.0364x; 1.1724x over previous
//
#include <hip/hip_runtime.h>
#include <math.h>

#define N_NODES 100000
#define N_EDGES 1600000
#define F_IN 256
#define F_H 128
#define F_OUT 40
#define SCAN_CHUNK 1024
#define NCHUNK ((N_NODES + SCAN_CHUNK - 1) / SCAN_CHUNK)   // 98

typedef __attribute__((ext_vector_type(8))) short bf16x8;
typedef __attribute__((ext_vector_type(4))) float floatx4;

__device__ __forceinline__ unsigned short f2bf(float f) {
    unsigned int u = __float_as_uint(f);
    u += 0x7fffu + ((u >> 16) & 1u);          // RNE (finite inputs)
    return (unsigned short)(u >> 16);
}
__device__ __forceinline__ float bf_lo(unsigned int u) { return __uint_as_float(u << 16); }
__device__ __forceinline__ float bf_hi(unsigned int u) { return __uint_as_float(u & 0xffff0000u); }
__device__ __forceinline__ float bf2f(unsigned short s) { return __uint_as_float(((unsigned int)s) << 16); }

// ---- zero int array ----
__global__ void k_zero(int* p, int n) {
    int i = blockIdx.x * blockDim.x + threadIdx.x;
    if (i < n) p[i] = 0;
}

// ---- int degree count over dst ----
__global__ void k_deg(const int* __restrict__ eidx, int* degi) {
    int e = blockIdx.x * blockDim.x + threadIdx.x;
    if (e < N_EDGES) atomicAdd(&degi[eidx[N_EDGES + e]], 1);
}

// ---- dinv = rsqrt(deg + 1 [self-loop]) ----
__global__ void k_dinv(const int* __restrict__ degi, float* __restrict__ dinv) {
    int i = blockIdx.x * blockDim.x + threadIdx.x;
    if (i < N_NODES) dinv[i] = rsqrtf((float)degi[i] + 1.0f);
}

// ---- scan level 1 ----
__global__ __launch_bounds__(256) void k_chunk_sums(const int* __restrict__ degi,
                                                    int* __restrict__ chunkSums) {
    __shared__ int lds[256];
    int b = blockIdx.x, t = threadIdx.x;
    int base = b * SCAN_CHUNK;
    int s = 0;
#pragma unroll
    for (int j = 0; j < 4; ++j) {
        int i = base + j * 256 + t;
        if (i < N_NODES) s += degi[i];
    }
    lds[t] = s;
    __syncthreads();
    for (int off = 128; off > 0; off >>= 1) {
        if (t < off) lds[t] += lds[t + off];
        __syncthreads();
    }
    if (t == 0) chunkSums[b] = lds[0];
}

// ---- scan level 2 ----
__global__ __launch_bounds__(128) void k_scan_sums(int* chunkSums) {
    __shared__ int lds[NCHUNK];
    int t = threadIdx.x;
    if (t < NCHUNK) lds[t] = chunkSums[t];
    __syncthreads();
    if (t == 0) {
        int run = 0;
        for (int i = 0; i < NCHUNK; ++i) { int c = lds[i]; lds[i] = run; run += c; }
    }
    __syncthreads();
    if (t < NCHUNK) chunkSums[t] = lds[t];
}

// ---- scan level 3 ----
__global__ __launch_bounds__(256) void k_scan_final(const int* __restrict__ degi,
                                                    const int* __restrict__ chunkOff,
                                                    int* __restrict__ rowptr,
                                                    int* __restrict__ cursor) {
    __shared__ int tsum[256];
    int b = blockIdx.x, t = threadIdx.x;
    int base = b * SCAN_CHUNK;
    int v[4];
    int s = 0;
#pragma unroll
    for (int j = 0; j < 4; ++j) {
        int i = base + t * 4 + j;
        v[j] = (i < N_NODES) ? degi[i] : 0;
        s += v[j];
    }
    tsum[t] = s;
    __syncthreads();
    for (int off = 1; off < 256; off <<= 1) {
        int val = 0;
        if (t >= off) val = tsum[t - off];
        __syncthreads();
        if (t >= off) tsum[t] += val;
        __syncthreads();
    }
    int run = chunkOff[b] + ((t == 0) ? 0 : tsum[t - 1]);
#pragma unroll
    for (int j = 0; j < 4; ++j) {
        int i = base + t * 4 + j;
        if (i < N_NODES) { rowptr[i] = run; cursor[i] = run; }
        run += v[j];
    }
    if (b == 0 && t == 0) rowptr[N_NODES] = N_EDGES;
}

// ---- CSR fill (also computes norm) ----
__global__ void k_fill(const int* __restrict__ eidx, const float* __restrict__ dinv,
                       int* cursor, int* __restrict__ csr_src, float* __restrict__ csr_norm) {
    int e = blockIdx.x * blockDim.x + threadIdx.x;
    if (e >= N_EDGES) return;
    int s = eidx[e], d = eidx[N_EDGES + e];
    int pos = atomicAdd(&cursor[d], 1);
    csr_src[pos] = s;
    csr_norm[pos] = dinv[s] * dinv[d];
}

// ---- W1 [256][128] fp32 -> W1t [128][256] bf16 ----
__global__ void k_cvt_w1(const float* __restrict__ W1, short* __restrict__ W1t) {
    int idx = blockIdx.x * blockDim.x + threadIdx.x;   // 32768
    int n = idx >> 8, k = idx & 255;
    W1t[n * 256 + k] = (short)f2bf(W1[k * 128 + n]);
}

// ---- W2 [128][40] fp32 -> W2t [48][128] bf16 (zero-padded cols 40..47) ----
__global__ void k_cvt_w2(const float* __restrict__ W2, short* __restrict__ W2t) {
    int idx = blockIdx.x * blockDim.x + threadIdx.x;   // 6144
    if (idx >= 48 * 128) return;
    int n = idx >> 7, k = idx & 127;
    float v = (n < F_OUT) ? W2[k * F_OUT + n] : 0.f;
    W2t[n * 128 + k] = (short)f2bf(v);
}

// ---- GEMM1 (MFMA bf16): h1b[N,128](bf16) = x[N,256] @ W1 ----
__global__ __launch_bounds__(256) void k_gemm1_mfma(const float* __restrict__ x,
                                                    const short* __restrict__ W1t,
                                                    unsigned short* __restrict__ h1b) {
    __shared__ short As[64 * 40];    // row stride 40 bf16 (80 B): 2-way banks, free
    __shared__ short Bs[128 * 40];
    const int tid = threadIdx.x;
    const int row0 = blockIdx.x * 64;
    const int w = tid >> 6, l = tid & 63;
    const int l15 = l & 15, q = l >> 4;
    const int ar = tid >> 2;             // 0..63
    const int ak = (tid & 3) * 8;        // 0,8,16,24
    const int bn = tid >> 1;             // 0..127
    const int bk = (tid & 1) * 16;

    floatx4 acc[4][2];
#pragma unroll
    for (int mt = 0; mt < 4; ++mt)
#pragma unroll
        for (int nt = 0; nt < 2; ++nt) acc[mt][nt] = (floatx4)0.f;

    const bool arow_ok = (row0 + ar) < N_NODES;
    const float* xp = x + (size_t)(row0 + ar) * F_IN;

    for (int k0 = 0; k0 < F_IN; k0 += 32) {
        bf16x8 av;
        if (arow_ok) {
            float4 f0 = *(const float4*)(xp + k0 + ak);
            float4 f1 = *(const float4*)(xp + k0 + ak + 4);
            av[0] = (short)f2bf(f0.x); av[1] = (short)f2bf(f0.y);
            av[2] = (short)f2bf(f0.z); av[3] = (short)f2bf(f0.w);
            av[4] = (short)f2bf(f1.x); av[5] = (short)f2bf(f1.y);
            av[6] = (short)f2bf(f1.z); av[7] = (short)f2bf(f1.w);
        } else {
            av = (bf16x8)0;
        }
        *(bf16x8*)&As[ar * 40 + ak] = av;
        *(bf16x8*)&Bs[bn * 40 + bk]     = *(const bf16x8*)&W1t[bn * 256 + k0 + bk];
        *(bf16x8*)&Bs[bn * 40 + bk + 8] = *(const bf16x8*)&W1t[bn * 256 + k0 + bk + 8];
        __syncthreads();

        bf16x8 af[4], bfr[2];
#pragma unroll
        for (int mt = 0; mt < 4; ++mt)
            af[mt] = *(const bf16x8*)&As[(mt * 16 + l15) * 40 + q * 8];
#pragma unroll
        for (int nt = 0; nt < 2; ++nt)
            bfr[nt] = *(const bf16x8*)&Bs[(w * 32 + nt * 16 + l15) * 40 + q * 8];
#pragma unroll
        for (int mt = 0; mt < 4; ++mt)
#pragma unroll
            for (int nt = 0; nt < 2; ++nt)
                acc[mt][nt] = __builtin_amdgcn_mfma_f32_16x16x32_bf16(af[mt], bfr[nt], acc[mt][nt], 0, 0, 0);
        __syncthreads();
    }
#pragma unroll
    for (int mt = 0; mt < 4; ++mt) {
#pragma unroll
        for (int nt = 0; nt < 2; ++nt) {
            int col = w * 32 + nt * 16 + l15;
#pragma unroll
            for (int r = 0; r < 4; ++r) {
                int row = row0 + mt * 16 + q * 4 + r;
                if (row < N_NODES) h1b[(size_t)row * F_H + col] = f2bf(acc[mt][nt][r]);
            }
        }
    }
}

// ---- SpMM1: wave per node, lane l = feature pair [2l,2l+1]; bf16 gather ----
__global__ __launch_bounds__(256) void k_spmm1(const int* __restrict__ rowptr,
                                               const int* __restrict__ csr_src,
                                               const float* __restrict__ csr_norm,
                                               const unsigned int* __restrict__ h1p,  // h1b as dwords
                                               const float* __restrict__ dinv,
                                               const float* __restrict__ b1,
                                               unsigned int* __restrict__ agg1p) {   // agg1b as dwords
    int wave = threadIdx.x >> 6;
    int node = blockIdx.x * 4 + wave;
    int l = threadIdx.x & 63;
    if (node >= N_NODES) return;
    int beg = rowptr[node], end = rowptr[node + 1];
    float d = dinv[node];
    unsigned int su = h1p[(size_t)node * 64 + l];
    float aL0 = bf_lo(su) * d * d, aH0 = bf_hi(su) * d * d;   // self loop
    float aL1 = 0.f, aH1 = 0.f, aL2 = 0.f, aH2 = 0.f, aL3 = 0.f, aH3 = 0.f;
    int i = beg;
    for (; i + 3 < end; i += 4) {
        int s0 = csr_src[i], s1 = csr_src[i + 1], s2 = csr_src[i + 2], s3 = csr_src[i + 3];
        float n0 = csr_norm[i], n1 = csr_norm[i + 1], n2 = csr_norm[i + 2], n3 = csr_norm[i + 3];
        unsigned int u0 = h1p[(size_t)s0 * 64 + l];
        unsigned int u1 = h1p[(size_t)s1 * 64 + l];
        unsigned int u2 = h1p[(size_t)s2 * 64 + l];
        unsigned int u3 = h1p[(size_t)s3 * 64 + l];
        aL0 = fmaf(bf_lo(u0), n0, aL0); aH0 = fmaf(bf_hi(u0), n0, aH0);
        aL1 = fmaf(bf_lo(u1), n1, aL1); aH1 = fmaf(bf_hi(u1), n1, aH1);
        aL2 = fmaf(bf_lo(u2), n2, aL2); aH2 = fmaf(bf_hi(u2), n2, aH2);
        aL3 = fmaf(bf_lo(u3), n3, aL3); aH3 = fmaf(bf_hi(u3), n3, aH3);
    }
    for (; i < end; ++i) {
        int s0 = csr_src[i];
        float n0 = csr_norm[i];
        unsigned int u0 = h1p[(size_t)s0 * 64 + l];
        aL0 = fmaf(bf_lo(u0), n0, aL0); aH0 = fmaf(bf_hi(u0), n0, aH0);
    }
    float vL = (aL0 + aL1) + (aL2 + aL3) + b1[2 * l];
    float vH = (aH0 + aH1) + (aH2 + aH3) + b1[2 * l + 1];
    vL = vL > 0.f ? vL : 0.f;
    vH = vH > 0.f ? vH : 0.f;
    agg1p[(size_t)node * 64 + l] = ((unsigned int)f2bf(vH) << 16) | f2bf(vL);
}

// ---- GEMM2 (MFMA bf16): h2b[N,40](bf16) = agg1b[N,128] @ W2 ----
__global__ __launch_bounds__(256) void k_gemm2_mfma(const unsigned short* __restrict__ agg1b,
                                                    const short* __restrict__ W2t,
                                                    unsigned short* __restrict__ h2b) {
    __shared__ short As[128 * 40];     // 10 KB
    __shared__ short Bs[48 * 136];     // 12.75 KB
    const int tid = threadIdx.x;
    const int row0 = blockIdx.x * 128;
    const int w = tid >> 6, l = tid & 63;
    const int l15 = l & 15, q = l >> 4;
    const int ar = tid >> 1;             // 0..127
    const int ak = (tid & 1) * 16;

#pragma unroll
    for (int i = 0; i < 3; ++i) {
        int c = tid * 3 + i;             // 0..767 chunks of 8 bf16
        int n = c >> 4, koff = (c & 15) * 8;
        *(bf16x8*)&Bs[n * 136 + koff] = *(const bf16x8*)&W2t[n * 128 + koff];
    }

    floatx4 acc[2][3];
#pragma unroll
    for (int a = 0; a < 2; ++a)
#pragma unroll
        for (int nt = 0; nt < 3; ++nt) acc[a][nt] = (floatx4)0.f;

    const bool arow_ok = (row0 + ar) < N_NODES;
    const unsigned short* ap = agg1b + (size_t)(row0 + ar) * F_H;

    for (int k0 = 0; k0 < F_H; k0 += 32) {
        bf16x8 a0, a1;
        if (arow_ok) {
            a0 = *(const bf16x8*)(ap + k0 + ak);
            a1 = *(const bf16x8*)(ap + k0 + ak + 8);
        } else {
            a0 = (bf16x8)0; a1 = (bf16x8)0;
        }
        *(bf16x8*)&As[ar * 40 + ak]     = a0;
        *(bf16x8*)&As[ar * 40 + ak + 8] = a1;
        __syncthreads();

        bf16x8 af[2], bfr[3];
#pragma unroll
        for (int a = 0; a < 2; ++a)
            af[a] = *(const bf16x8*)&As[((w * 2 + a) * 16 + l15) * 40 + q * 8];
#pragma unroll
        for (int nt = 0; nt < 3; ++nt)
            bfr[nt] = *(const bf16x8*)&Bs[(nt * 16 + l15) * 136 + k0 + q * 8];
#pragma unroll
        for (int a = 0; a < 2; ++a)
#pragma unroll
            for (int nt = 0; nt < 3; ++nt)
                acc[a][nt] = __builtin_amdgcn_mfma_f32_16x16x32_bf16(af[a], bfr[nt], acc[a][nt], 0, 0, 0);
        __syncthreads();
    }
#pragma unroll
    for (int a = 0; a < 2; ++a) {
#pragma unroll
        for (int nt = 0; nt < 3; ++nt) {
            int col = nt * 16 + l15;
#pragma unroll
            for (int r = 0; r < 4; ++r) {
                int row = row0 + (w * 2 + a) * 16 + q * 4 + r;
                if (row < N_NODES && col < F_OUT)
                    h2b[(size_t)row * F_OUT + col] = f2bf(acc[a][nt][r]);
            }
        }
    }
}

// ---- SpMM2 (bf16 gather) + self-loop + b2 + log_softmax, wave per node ----
__global__ __launch_bounds__(256) void k_spmm2_lsm(const int* __restrict__ rowptr,
                                                   const int* __restrict__ csr_src,
                                                   const float* __restrict__ csr_norm,
                                                   const unsigned short* __restrict__ h2b,
                                                   const float* __restrict__ dinv,
                                                   const float* __restrict__ b2,
                                                   float* __restrict__ out) {
    int wave = threadIdx.x >> 6;
    int node = blockIdx.x * 4 + wave;
    int lane = threadIdx.x & 63;
    if (node >= N_NODES) return;
    int beg = rowptr[node], end = rowptr[node + 1];
    float d = dinv[node];
    const bool act = lane < F_OUT;
    float a0 = 0.f, a1 = 0.f, a2 = 0.f, a3 = 0.f;
    if (act) a0 = bf2f(h2b[(size_t)node * F_OUT + lane]) * d * d;
    int i = beg;
    for (; i + 3 < end; i += 4) {
        int s0 = csr_src[i], s1 = csr_src[i + 1], s2 = csr_src[i + 2], s3 = csr_src[i + 3];
        float n0 = csr_norm[i], n1 = csr_norm[i + 1], n2 = csr_norm[i + 2], n3 = csr_norm[i + 3];
        if (act) {
            a0 = fmaf(bf2f(h2b[(size_t)s0 * F_OUT + lane]), n0, a0);
            a1 = fmaf(bf2f(h2b[(size_t)s1 * F_OUT + lane]), n1, a1);
            a2 = fmaf(bf2f(h2b[(size_t)s2 * F_OUT + lane]), n2, a2);
            a3 = fmaf(bf2f(h2b[(size_t)s3 * F_OUT + lane]), n3, a3);
        }
    }
    for (; i < end; ++i) {
        if (act) a0 = fmaf(bf2f(h2b[(size_t)csr_src[i] * F_OUT + lane]), csr_norm[i], a0);
    }
    float v = act ? (a0 + a1) + (a2 + a3) + b2[lane] : -INFINITY;
    float m = v;
#pragma unroll
    for (int o = 32; o > 0; o >>= 1) m = fmaxf(m, __shfl_xor(m, o, 64));
    float ev = act ? expf(v - m) : 0.f;
    float ssum = ev;
#pragma unroll
    for (int o = 32; o > 0; o >>= 1) ssum += __shfl_xor(ssum, o, 64);
    if (act) out[(size_t)node * F_OUT + lane] = v - m - logf(ssum);
}

extern "C" void kernel_launch(void* const* d_in, const int* in_sizes, int n_in,
                              void* d_out, int out_size, void* d_ws, size_t ws_size,
                              hipStream_t stream) {
    const float* x = (const float*)d_in[0];
    const int* eidx = (const int*)d_in[1];   // int32 from harness
    const float* W1 = (const float*)d_in[2];
    const float* b1 = (const float*)d_in[3];
    const float* W2 = (const float*)d_in[4];
    const float* b2 = (const float*)d_in[5];
    float* out = (float*)d_out;

    char* ws = (char*)d_ws;
    int*   degi      = (int*)  (ws);                 // 100000 ints
    int*   chunkSums = (int*)  (ws + 400000);        // 128
    int*   rowptr    = (int*)  (ws + 400512);        // 100001
    int*   cursor    = (int*)  (ws + 800528);        // 100000
    int*   csr_src   = (int*)  (ws + 1200528);       // 1.6M
    float* csr_norm  = (float*)(ws + 7600528);       // 1.6M
    float* dinv      = (float*)(ws + 14000528);      // 100000
    short* W1t       = (short*)(ws + 14400528);      // 32768 bf16
    short* W2t       = (short*)(ws + 14466064);      // 6144 bf16
    unsigned short* h1b   = (unsigned short*)(ws + 14478352);  // 12.8M bf16 (25.6 MB)
    unsigned short* agg1b = (unsigned short*)(ws + 40078352);  // 12.8M bf16 (25.6 MB)
    unsigned short* h2b   = (unsigned short*)(ws + 65678352);  // 4M bf16 (8 MB)

    k_zero<<<(N_NODES + 255) / 256, 256, 0, stream>>>(degi, N_NODES);
    k_deg<<<(N_EDGES + 255) / 256, 256, 0, stream>>>(eidx, degi);
    k_dinv<<<(N_NODES + 255) / 256, 256, 0, stream>>>(degi, dinv);
    k_chunk_sums<<<NCHUNK, 256, 0, stream>>>(degi, chunkSums);
    k_scan_sums<<<1, 128, 0, stream>>>(chunkSums);
    k_scan_final<<<NCHUNK, 256, 0, stream>>>(degi, chunkSums, rowptr, cursor);
    k_fill<<<(N_EDGES + 255) / 256, 256, 0, stream>>>(eidx, dinv, cursor, csr_src, csr_norm);

    k_cvt_w1<<<128, 256, 0, stream>>>(W1, W1t);
    k_cvt_w2<<<24, 256, 0, stream>>>(W2, W2t);

    k_gemm1_mfma<<<(N_NODES + 63) / 64, 256, 0, stream>>>(x, W1t, h1b);
    k_spmm1<<<(N_NODES + 3) / 4, 256, 0, stream>>>(rowptr, csr_src, csr_norm,
                                                   (const unsigned int*)h1b, dinv, b1,
                                                   (unsigned int*)agg1b);
    k_gemm2_mfma<<<(N_NODES + 127) / 128, 256, 0, stream>>>(agg1b, W2t, h2b);
    k_spmm2_lsm<<<(N_NODES + 3) / 4, 256, 0, stream>>>(rowptr, csr_src, csr_norm, h2b, dinv, b2, out);
}